// Round 5
// baseline (332.075 us; speedup 1.0000x reference)
//
#include <hip/hip_runtime.h>
#include <stdint.h>

// Problem constants
#define DIMD 512
#define HEADS 8
#define DHEAD 64
#define NSEQ 256
#define NGRP 256                 // b*p = 4*64
#define NROWS (NGRP * NSEQ)      // 65536
#define TRIPLE 1536
#define ATT_SCALE 0.125f         // 64^-0.5

typedef float f32x4 __attribute__((ext_vector_type(4)));
typedef _Float16 half8 __attribute__((ext_vector_type(8)));
typedef _Float16 half4 __attribute__((ext_vector_type(4)));

// async global->LDS, 16B per lane; LDS dest = uniform base + lane*16
#define GLD16(gp, lp) __builtin_amdgcn_global_load_lds( \
    (const __attribute__((address_space(1))) void*)(gp), \
    (__attribute__((address_space(3))) void*)(lp), 16, 0, 0)

// ---------------------------------------------------------------------------
// Kernel 0: convert weights fp32 -> fp16, transposed to [out][in] (B^T) layout
// ---------------------------------------------------------------------------
__global__ __launch_bounds__(256) void k_wconv(const float* __restrict__ wq,
                                               const float* __restrict__ wo,
                                               _Float16* __restrict__ wtq,
                                               _Float16* __restrict__ wto) {
  int id = blockIdx.x * 256 + threadIdx.x;   // grid covers exactly 786432+262144
  if (id < DIMD * TRIPLE) {
    int k = id / TRIPLE, n = id % TRIPLE;
    wtq[n * DIMD + k] = (_Float16)wq[id];
  } else {
    int j = id - DIMD * TRIPLE;
    int k = j / DIMD, n = j % DIMD;
    wto[n * DIMD + k] = (_Float16)wo[j];
  }
}

// ---------------------------------------------------------------------------
// Kernel 1: LayerNorm, one wave per row (512 floats), write half
// ---------------------------------------------------------------------------
__global__ __launch_bounds__(256) void k_ln(const float* __restrict__ x,
                                            const float* __restrict__ g,
                                            const float* __restrict__ b,
                                            _Float16* __restrict__ xn) {
  int row = blockIdx.x * 4 + (threadIdx.x >> 6);
  int lane = threadIdx.x & 63;
  const float* xr = x + (size_t)row * DIMD + lane * 8;
  float v[8];
  *(f32x4*)(v)     = *(const f32x4*)(xr);
  *(f32x4*)(v + 4) = *(const f32x4*)(xr + 4);
  float s = 0.f, ss = 0.f;
#pragma unroll
  for (int j = 0; j < 8; ++j) { s += v[j]; ss += v[j] * v[j]; }
#pragma unroll
  for (int m = 1; m < 64; m <<= 1) { s += __shfl_xor(s, m); ss += __shfl_xor(ss, m); }
  float mean = s * (1.f / DIMD);
  float var  = ss * (1.f / DIMD) - mean * mean;
  float rstd = rsqrtf(var + 1e-5f);
  const float* gp = g + lane * 8;
  const float* bp = b + lane * 8;
  half8 o;
#pragma unroll
  for (int j = 0; j < 8; ++j) o[j] = (_Float16)((v[j] - mean) * rstd * gp[j] + bp[j]);
  *(half8*)(xn + (size_t)row * DIMD + lane * 8) = o;
}

// ---------------------------------------------------------------------------
// Kernel 2/4: GEMM C[M,N] = A[M,512] * BT[N,512]^T   (m97-style 128x128, BK=64)
// A has row stride LDA. WITH_BIAS: C is FLOAT32 (final output) + f32 bias;
// else C is fp16.
// ---------------------------------------------------------------------------
template <int N, int LDA, bool WITH_BIAS>
__global__ __launch_bounds__(256, 2) void k_gemm(const _Float16* __restrict__ A,
                                                 const _Float16* __restrict__ BT,
                                                 _Float16* __restrict__ Ch,
                                                 float* __restrict__ Cf,
                                                 const float* __restrict__ bias) {
  constexpr int NT = N / 128;
  int mt = blockIdx.x / NT, nt = blockIdx.x % NT;
  int m0 = mt * 128, n0 = nt * 128;
  int tid = threadIdx.x, lane = tid & 63, w = tid >> 6;
  int wr = w >> 1, wc = w & 1;
  int l15 = lane & 15, lg = lane >> 4;
  __shared__ _Float16 Asm[128 * 64];
  __shared__ _Float16 Bsm[128 * 64];
  f32x4 acc[4][4] = {};
  const int rA = lane >> 3;
  const int cA = (lane & 7) * 8;

  for (int ks = 0; ks < 8; ++ks) {
    int k0 = ks * 64;
#pragma unroll
    for (int i = 0; i < 4; ++i) {
      int r0 = w * 32 + i * 8;
      GLD16(A  + (size_t)(m0 + r0 + rA) * LDA + k0 + cA, &Asm[r0 * 64]);
      GLD16(BT + (size_t)(n0 + r0 + rA) * 512 + k0 + cA, &Bsm[r0 * 64]);
    }
    __syncthreads();
#pragma unroll
    for (int kk = 0; kk < 2; ++kk) {
      int co = kk * 32 + lg * 8;
      half8 a[4], b[4];
#pragma unroll
      for (int m = 0; m < 4; ++m) a[m] = *(const half8*)&Asm[(wr * 64 + m * 16 + l15) * 64 + co];
#pragma unroll
      for (int n = 0; n < 4; ++n) b[n] = *(const half8*)&Bsm[(wc * 64 + n * 16 + l15) * 64 + co];
#pragma unroll
      for (int m = 0; m < 4; ++m)
#pragma unroll
        for (int n = 0; n < 4; ++n)
          acc[m][n] = __builtin_amdgcn_mfma_f32_16x16x32_f16(a[m], b[n], acc[m][n], 0, 0, 0);
    }
    __syncthreads();
  }

  int rowb = m0 + wr * 64 + lg * 4;
  int colb = n0 + wc * 64 + l15;
  float bb[4];
  if constexpr (WITH_BIAS) {
#pragma unroll
    for (int n = 0; n < 4; ++n) bb[n] = bias[colb + n * 16];
  }
#pragma unroll
  for (int m = 0; m < 4; ++m)
#pragma unroll
    for (int n = 0; n < 4; ++n)
#pragma unroll
      for (int r = 0; r < 4; ++r) {
        size_t idx = (size_t)(rowb + m * 16 + r) * N + colb + n * 16;
        if constexpr (WITH_BIAS)
          Cf[idx] = acc[m][n][r] + bb[n];
        else
          Ch[idx] = (_Float16)acc[m][n][r];
      }
}

// ---------------------------------------------------------------------------
// Kernel 3: fused attention, one block per (group, head). 4 waves x 64 q-rows.
// Swapped QK^T: st = mfma(K, Q) => lane holds P[q = nq*16+l15][key = mk*16+lg*4+r]
// so softmax reduce = 2 shuffles and P stores contiguously.
// Output is written back into the (dead) Q columns of qkv (stride TRIPLE):
// each block's Q is register-resident before its writes, and blocks touch
// disjoint (rows x head-columns), so the in-place write is race-free.
// ---------------------------------------------------------------------------
__global__ __launch_bounds__(256, 2) void k_attn(_Float16* __restrict__ qkv) {
  int g = blockIdx.x >> 3, h = blockIdx.x & 7;
  int tid = threadIdx.x, lane = tid & 63, w = tid >> 6;
  int l15 = lane & 15, lg = lane >> 4;
  __shared__ _Float16 Kt[64 * 72];          // [key][dh], padded rows (72)
  __shared__ _Float16 Vt[64 * 72];          // [dh][key] (transposed), padded
  __shared__ _Float16 Pl[4][64 * 72];       // per-wave P[q][key], padded
  const size_t base = (size_t)g * NSEQ * TRIPLE;

  // Q fragments (B-operand layout): q col = l15 + nq*16, dh contiguous
  half8 qf[4][2];
#pragma unroll
  for (int nq = 0; nq < 4; ++nq)
#pragma unroll
    for (int kd = 0; kd < 2; ++kd)
      qf[nq][kd] = *(const half8*)&qkv[base + (size_t)(w * 64 + nq * 16 + l15) * TRIPLE
                                       + h * 64 + kd * 32 + lg * 8];

  f32x4 oacc[4][4] = {};
  float mrun[4], lrun[4];
#pragma unroll
  for (int nq = 0; nq < 4; ++nq) { mrun[nq] = -3.0e38f; lrun[nq] = 0.f; }

  for (int kt = 0; kt < 4; ++kt) {
    __syncthreads();     // protect LDS overwrite vs previous iteration's PV
    // stage K tile [64][64] and V^T tile [64][64] for this key block
#pragma unroll
    for (int i = 0; i < 2; ++i) {
      int idx = tid + i * 256;               // 0..511
      int key = idx >> 3, dh0 = (idx & 7) * 8;
      half8 kv = *(const half8*)&qkv[base + (size_t)(kt * 64 + key) * TRIPLE + 512 + h * 64 + dh0];
      *(half8*)&Kt[key * 72 + dh0] = kv;
      half8 vv = *(const half8*)&qkv[base + (size_t)(kt * 64 + key) * TRIPLE + 1024 + h * 64 + dh0];
#pragma unroll
      for (int j = 0; j < 8; ++j) Vt[(dh0 + j) * 72 + key] = vv[j];
    }
    __syncthreads();

    // S^T = K * Q^T
    f32x4 st[4][4] = {};
#pragma unroll
    for (int kd = 0; kd < 2; ++kd) {
      int co = kd * 32 + lg * 8;
      half8 kf[4];
#pragma unroll
      for (int mk = 0; mk < 4; ++mk) kf[mk] = *(const half8*)&Kt[(mk * 16 + l15) * 72 + co];
#pragma unroll
      for (int mk = 0; mk < 4; ++mk)
#pragma unroll
        for (int nq = 0; nq < 4; ++nq)
          st[mk][nq] = __builtin_amdgcn_mfma_f32_16x16x32_f16(kf[mk], qf[nq][kd], st[mk][nq], 0, 0, 0);
    }

    // online softmax per q column (nq, l15); key axis = (mk, lg, r)
    float alpha[4];
#pragma unroll
    for (int nq = 0; nq < 4; ++nq) {
      float pm = -3.0e38f;
#pragma unroll
      for (int mk = 0; mk < 4; ++mk)
#pragma unroll
        for (int r = 0; r < 4; ++r) {
          st[mk][nq][r] *= ATT_SCALE;
          pm = fmaxf(pm, st[mk][nq][r]);
        }
      pm = fmaxf(pm, __shfl_xor(pm, 16));
      pm = fmaxf(pm, __shfl_xor(pm, 32));
      float mn = fmaxf(mrun[nq], pm);
      alpha[nq] = __expf(mrun[nq] - mn);
      mrun[nq] = mn;
      float ps = 0.f;
#pragma unroll
      for (int mk = 0; mk < 4; ++mk) {
        half4 p4;
#pragma unroll
        for (int r = 0; r < 4; ++r) {
          float e = __expf(st[mk][nq][r] - mn);
          ps += e;
          p4[r] = (_Float16)e;
        }
        // P[q = nq*16+l15][keys mk*16+lg*4 .. +4] contiguous
        *(half4*)&Pl[w][(nq * 16 + l15) * 72 + mk * 16 + lg * 4] = p4;
      }
      ps += __shfl_xor(ps, 16);
      ps += __shfl_xor(ps, 32);
      lrun[nq] = lrun[nq] * alpha[nq] + ps;
    }

    // rescale O: O row q = mp*16 + lg*4 + r, alpha lives at lanes l15 == q&15
#pragma unroll
    for (int mp = 0; mp < 4; ++mp)
#pragma unroll
      for (int r = 0; r < 4; ++r) {
        float av = __shfl(alpha[mp], lg * 4 + r);
#pragma unroll
        for (int nd = 0; nd < 4; ++nd) oacc[mp][nd][r] *= av;
      }

    __syncthreads();   // P visible (also keeps waves in lockstep)

    // O += P * V
#pragma unroll
    for (int kp = 0; kp < 2; ++kp) {
      int co = kp * 32 + lg * 8;
      half8 pf[4], vf[4];
#pragma unroll
      for (int mp = 0; mp < 4; ++mp) pf[mp] = *(const half8*)&Pl[w][(mp * 16 + l15) * 72 + co];
#pragma unroll
      for (int nd = 0; nd < 4; ++nd) vf[nd] = *(const half8*)&Vt[(nd * 16 + l15) * 72 + co];
#pragma unroll
      for (int mp = 0; mp < 4; ++mp)
#pragma unroll
        for (int nd = 0; nd < 4; ++nd)
          oacc[mp][nd] = __builtin_amdgcn_mfma_f32_16x16x32_f16(pf[mp], vf[nd], oacc[mp][nd], 0, 0, 0);
    }
  }

  // epilogue: normalize and write att into the Q columns (stride TRIPLE)
#pragma unroll
  for (int mp = 0; mp < 4; ++mp)
#pragma unroll
    for (int r = 0; r < 4; ++r) {
      float li = 1.f / __shfl(lrun[mp], lg * 4 + r);
      int q = w * 64 + mp * 16 + lg * 4 + r;
#pragma unroll
      for (int nd = 0; nd < 4; ++nd)
        qkv[base + (size_t)q * TRIPLE + h * 64 + nd * 16 + l15] =
            (_Float16)(oacc[mp][nd][r] * li);
    }
}

// ---------------------------------------------------------------------------
extern "C" void kernel_launch(void* const* d_in, const int* in_sizes, int n_in,
                              void* d_out, int out_size, void* d_ws, size_t ws_size,
                              hipStream_t stream) {
  const float* x     = (const float*)d_in[0];
  const float* ln_g  = (const float*)d_in[1];
  const float* ln_b  = (const float*)d_in[2];
  const float* w_qkv = (const float*)d_in[3];
  const float* w_out = (const float*)d_in[4];
  const float* b_out = (const float*)d_in[5];

  // workspace layout (~194 MB):
  //   [0, 192M)        qkv fp16 [65536][1536]; att overwrites its Q columns
  //   [192M, +1.5M)    w_qkv^T fp16 [1536][512]
  //   [+1.5M, +0.5M)   w_out^T fp16 [512][512]
  // d_out is FLOAT32 [65536][512] (128 MB); its first 64MB double as xn fp16
  // scratch until the final GEMM overwrites all of it.
  char* ws = (char*)d_ws;
  _Float16* qkv = (_Float16*)ws;
  _Float16* wtq = (_Float16*)(ws + 201326592ull);
  _Float16* wto = (_Float16*)(ws + 201326592ull + 1572864ull);
  _Float16* xn  = (_Float16*)d_out;     // fp16 scratch inside f32 out buffer
  float* out    = (float*)d_out;        // final f32 output

  k_wconv<<<4096, 256, 0, stream>>>(w_qkv, w_out, wtq, wto);
  k_ln<<<16384, 256, 0, stream>>>(x, ln_g, ln_b, xn);
  k_gemm<TRIPLE, DIMD, false><<<6144, 256, 0, stream>>>(xn, wtq, qkv, nullptr, nullptr);
  k_attn<<<2048, 256, 0, stream>>>(qkv);
  k_gemm<DIMD, TRIPLE, true><<<2048, 256, 0, stream>>>(qkv, wto, nullptr, out, b_out);
}

// Round 7
// 306.693 us; speedup vs baseline: 1.0828x; 1.0828x over previous
//
#include <hip/hip_runtime.h>
#include <stdint.h>

// Problem constants
#define DIMD 512
#define HEADS 8
#define DHEAD 64
#define NSEQ 256
#define NGRP 256                 // b*p = 4*64
#define TRIPLE 1536
#define ATT_SCALE 0.125f         // 64^-0.5

typedef float f32x4 __attribute__((ext_vector_type(4)));
typedef _Float16 half8 __attribute__((ext_vector_type(8)));
typedef _Float16 half4 __attribute__((ext_vector_type(4)));

// async global->LDS, 16B per lane; LDS dest = uniform base + lane*16
#define GLD16(gp, lp) __builtin_amdgcn_global_load_lds( \
    (const __attribute__((address_space(1))) void*)(gp), \
    (__attribute__((address_space(3))) void*)(lp), 16, 0, 0)
#define BAR() __builtin_amdgcn_s_barrier()
#define VMW(n) asm volatile("s_waitcnt vmcnt(" #n ")" ::: "memory")

// ---------------------------------------------------------------------------
// Kernel 0: convert weights fp32 -> fp16, transposed to [out][in] (B^T) layout
// ---------------------------------------------------------------------------
__global__ __launch_bounds__(256) void k_wconv(const float* __restrict__ wq,
                                               const float* __restrict__ wo,
                                               _Float16* __restrict__ wtq,
                                               _Float16* __restrict__ wto) {
  int id = blockIdx.x * 256 + threadIdx.x;   // grid covers exactly 786432+262144
  if (id < DIMD * TRIPLE) {
    int k = id / TRIPLE, n = id % TRIPLE;
    wtq[n * DIMD + k] = (_Float16)wq[id];
  } else {
    int j = id - DIMD * TRIPLE;
    int k = j / DIMD, n = j % DIMD;
    wto[n * DIMD + k] = (_Float16)wo[j];
  }
}

// ---------------------------------------------------------------------------
// Kernel 1: LayerNorm, one wave per row (512 floats), write half
// ---------------------------------------------------------------------------
__global__ __launch_bounds__(256) void k_ln(const float* __restrict__ x,
                                            const float* __restrict__ g,
                                            const float* __restrict__ b,
                                            _Float16* __restrict__ xn) {
  int row = blockIdx.x * 4 + (threadIdx.x >> 6);
  int lane = threadIdx.x & 63;
  const float* xr = x + (size_t)row * DIMD + lane * 8;
  float v[8];
  *(f32x4*)(v)     = *(const f32x4*)(xr);
  *(f32x4*)(v + 4) = *(const f32x4*)(xr + 4);
  float s = 0.f, ss = 0.f;
#pragma unroll
  for (int j = 0; j < 8; ++j) { s += v[j]; ss += v[j] * v[j]; }
#pragma unroll
  for (int m = 1; m < 64; m <<= 1) { s += __shfl_xor(s, m); ss += __shfl_xor(ss, m); }
  float mean = s * (1.f / DIMD);
  float var  = ss * (1.f / DIMD) - mean * mean;
  float rstd = rsqrtf(var + 1e-5f);
  const float* gp = g + lane * 8;
  const float* bp = b + lane * 8;
  half8 o;
#pragma unroll
  for (int j = 0; j < 8; ++j) o[j] = (_Float16)((v[j] - mean) * rstd * gp[j] + bp[j]);
  *(half8*)(xn + (size_t)row * DIMD + lane * 8) = o;
}

// ---------------------------------------------------------------------------
// Kernel 2: 256x256-tile, BK=64, 8-wave (2Mx4N), phase-split GEMM.
// T1 XCD swizzle, T2 both-sides LDS XOR swizzle, T3+T4 counted vmcnt,
// T5 setprio. Staged "halves" are defined by the bit the quadrant loop
// varies (A: row bit6 == mh; B: row bit5 == nh) so the landing order
// matches every wave's consumption order (the round-6 NaN was this
// mismatch: halves-by-address vs quadrants-by-wave).
// ---------------------------------------------------------------------------
template <int N, int LDA>
__global__ __launch_bounds__(512, 2) void k_gemm8(const _Float16* __restrict__ A,
                                                  const _Float16* __restrict__ BT,
                                                  _Float16* __restrict__ C) {
  constexpr int NT = N / 256;
  constexpr int NWG = 256 * NT;          // 65536/256 m-tiles * NT; NWG % 8 == 0
  constexpr int CPX = NWG / 8;
  int b = blockIdx.x;
  int logical = (b & 7) * CPX + (b >> 3);  // bijective XCD chunking (T1)
  int mt = logical / NT, nt = logical % NT;
  int m0 = mt * 256, n0 = nt * 256;

  int tid = threadIdx.x, lane = tid & 63, w = tid >> 6;   // 8 waves
  int wrow = w >> 2, wcol = w & 3;                        // 2M x 4N
  int l15 = lane & 15, lg = lane >> 4;
  const int sr = lane >> 3;     // staging: row within 8-row stripe
  const int ss = lane & 7;      // staging: 16B slot within 128B row

  // 128 KiB LDS: [buf0: A 16384h | B 16384h][buf1: ...]
  __shared__ _Float16 S[65536];

  f32x4 acc[8][4] = {};          // [mh*4+mf][nh*2+nf]
  half8 af[4][2], bf0[2][2], bf1[2][2];

  // --- staging: A-half-hf = rows with bit6==hf ({0..63,128..191} / rest)
  auto stageA = [&](int d, int kt, int hf) {
#pragma unroll
    for (int cc = 0; cc < 2; ++cc) {
      int rbase = cc * 128 + hf * 64 + w * 8;          // 8-row stripe base
      const _Float16* g = A + (size_t)(m0 + rbase + sr) * LDA + kt * 64 + (ss ^ sr) * 8;
      _Float16* l = &S[d * 32768 + rbase * 64];
      GLD16(g, l);
    }
  };
  // --- staging: B-half-hf = rows with bit5==hf
  auto stageB = [&](int d, int kt, int hf) {
#pragma unroll
    for (int cc = 0; cc < 2; ++cc) {
      int i = cc * 64 + w * 8;                         // stripe index in [0,128)
      int rbase = (i >> 5) * 64 + hf * 32 + (i & 31);  // 8-row stripe base
      const _Float16* g = BT + (size_t)(n0 + rbase + sr) * 512 + kt * 64 + (ss ^ sr) * 8;
      _Float16* l = &S[d * 32768 + 16384 + rbase * 64];
      GLD16(g, l);
    }
  };
  // --- LDS -> register fragments (swizzled read, matches source permutation)
  auto loadA = [&](int c, int mh) {
#pragma unroll
    for (int mf = 0; mf < 4; ++mf) {
      int row = wrow * 128 + mh * 64 + mf * 16 + l15;  // bit6 == mh
#pragma unroll
      for (int kk = 0; kk < 2; ++kk) {
        int byte = row * 128 + ((kk * 64 + lg * 16) ^ ((row & 7) << 4));
        af[mf][kk] = *(const half8*)((const char*)&S[c * 32768] + byte);
      }
    }
  };
  auto loadB = [&](int c, int nh, half8 (&bf)[2][2]) {
#pragma unroll
    for (int nf = 0; nf < 2; ++nf) {
      int row = wcol * 64 + nh * 32 + nf * 16 + l15;   // bit5 == nh
#pragma unroll
      for (int kk = 0; kk < 2; ++kk) {
        int byte = row * 128 + ((kk * 64 + lg * 16) ^ ((row & 7) << 4));
        bf[nf][kk] = *(const half8*)((const char*)&S[c * 32768 + 16384] + byte);
      }
    }
  };
  auto quad = [&](int mh, int nh, half8 (&bf)[2][2]) {
    __builtin_amdgcn_s_setprio(1);
#pragma unroll
    for (int mf = 0; mf < 4; ++mf)
#pragma unroll
      for (int nf = 0; nf < 2; ++nf)
#pragma unroll
        for (int kk = 0; kk < 2; ++kk)
          acc[mh * 4 + mf][nh * 2 + nf] = __builtin_amdgcn_mfma_f32_16x16x32_f16(
              af[mf][kk], bf[nf][kk], acc[mh * 4 + mf][nh * 2 + nf], 0, 0, 0);
    __builtin_amdgcn_s_setprio(0);
  };

  // --- prologue: stage tile 0; order A0,B0,B1,A1 so VMW(4) => A-h0,B-h0 landed
  stageA(0, 0, 0); stageB(0, 0, 0); stageB(0, 0, 1); stageA(0, 0, 1);
  VMW(4); BAR();

  // --- main loop: consume tile t (buffer c), stage t+1 (buffer d).
  // FIFO invariant at entry: [B-h1(t):2, A-h1(t):2]
  for (int t = 0; t < 7; ++t) {
    int c = t & 1, d = c ^ 1;
    // ph1: needs A-h0,B-h0 (landed)
    loadA(c, 0); loadB(c, 0, bf0);
    stageA(d, t + 1, 0);
    BAR(); quad(0, 0, bf0); VMW(4); BAR();   // -> B-h1(t) landed
    // ph2: needs B-h1
    loadB(c, 1, bf1);
    stageB(d, t + 1, 0);
    BAR(); quad(0, 1, bf1); VMW(4); BAR();   // -> A-h1(t) landed
    // ph3: needs A-h1
    loadA(c, 1);
    stageB(d, t + 1, 1);
    BAR(); quad(1, 0, bf0); BAR();           // ph4 reads no LDS: no wait
    // ph4
    stageA(d, t + 1, 1);
    BAR(); quad(1, 1, bf1); VMW(4); BAR();   // -> A-h0,B-h0(t+1) landed
  }
  // --- last tile t=7 (c=1): no staging; drain just-in-time
  {
    loadA(1, 0); loadB(1, 0, bf0);
    BAR(); quad(0, 0, bf0); VMW(2); BAR();   // -> B-h1(7) landed
    loadB(1, 1, bf1);
    BAR(); quad(0, 1, bf1); VMW(0); BAR();   // -> A-h1(7) landed
    loadA(1, 1);
    BAR(); quad(1, 0, bf0); BAR();
    BAR(); quad(1, 1, bf1); BAR();
  }

  // --- epilogue
#pragma unroll
  for (int mq = 0; mq < 8; ++mq)
#pragma unroll
    for (int nq = 0; nq < 4; ++nq)
#pragma unroll
      for (int r = 0; r < 4; ++r) {
        int row = m0 + wrow * 128 + (mq >> 2) * 64 + (mq & 3) * 16 + lg * 4 + r;
        int col = n0 + wcol * 64 + (nq >> 1) * 32 + (nq & 1) * 16 + l15;
        C[(size_t)row * N + col] = (_Float16)acc[mq][nq][r];
      }
}

// ---------------------------------------------------------------------------
// Kernel 4: verified 128x128 GEMM (out-projection), + T1 XCD swizzle.
// WITH_BIAS: C is FLOAT32 (final output) + f32 bias; else C is fp16.
// ---------------------------------------------------------------------------
template <int N, int LDA, bool WITH_BIAS>
__global__ __launch_bounds__(256, 2) void k_gemm(const _Float16* __restrict__ A,
                                                 const _Float16* __restrict__ BT,
                                                 _Float16* __restrict__ Ch,
                                                 float* __restrict__ Cf,
                                                 const float* __restrict__ bias) {
  constexpr int NT = N / 128;
  constexpr int NWG = 512 * NT;        // M/128 = 512 m-tiles
  constexpr int CPX = NWG / 8;
  int bsw = (blockIdx.x & 7) * CPX + (blockIdx.x >> 3);   // T1
  int mt = bsw / NT, nt = bsw % NT;
  int m0 = mt * 128, n0 = nt * 128;
  int tid = threadIdx.x, lane = tid & 63, w = tid >> 6;
  int wr = w >> 1, wc = w & 1;
  int l15 = lane & 15, lg = lane >> 4;
  __shared__ _Float16 Asm[128 * 64];
  __shared__ _Float16 Bsm[128 * 64];
  f32x4 acc[4][4] = {};
  const int rA = lane >> 3;
  const int cA = (lane & 7) * 8;

  for (int ks = 0; ks < 8; ++ks) {
    int k0 = ks * 64;
#pragma unroll
    for (int i = 0; i < 4; ++i) {
      int r0 = w * 32 + i * 8;
      GLD16(A  + (size_t)(m0 + r0 + rA) * LDA + k0 + cA, &Asm[r0 * 64]);
      GLD16(BT + (size_t)(n0 + r0 + rA) * 512 + k0 + cA, &Bsm[r0 * 64]);
    }
    __syncthreads();
#pragma unroll
    for (int kk = 0; kk < 2; ++kk) {
      int co = kk * 32 + lg * 8;
      half8 a[4], b[4];
#pragma unroll
      for (int m = 0; m < 4; ++m) a[m] = *(const half8*)&Asm[(wr * 64 + m * 16 + l15) * 64 + co];
#pragma unroll
      for (int n = 0; n < 4; ++n) b[n] = *(const half8*)&Bsm[(wc * 64 + n * 16 + l15) * 64 + co];
#pragma unroll
      for (int m = 0; m < 4; ++m)
#pragma unroll
        for (int n = 0; n < 4; ++n)
          acc[m][n] = __builtin_amdgcn_mfma_f32_16x16x32_f16(a[m], b[n], acc[m][n], 0, 0, 0);
    }
    __syncthreads();
  }

  int rowb = m0 + wr * 64 + lg * 4;
  int colb = n0 + wc * 64 + l15;
  float bb[4];
  if constexpr (WITH_BIAS) {
#pragma unroll
    for (int n = 0; n < 4; ++n) bb[n] = bias[colb + n * 16];
  }
#pragma unroll
  for (int m = 0; m < 4; ++m)
#pragma unroll
    for (int n = 0; n < 4; ++n)
#pragma unroll
      for (int r = 0; r < 4; ++r) {
        size_t idx = (size_t)(rowb + m * 16 + r) * N + colb + n * 16;
        if constexpr (WITH_BIAS)
          Cf[idx] = acc[m][n][r] + bb[n];
        else
          Ch[idx] = (_Float16)acc[m][n][r];
      }
}

// ---------------------------------------------------------------------------
// Kernel 3: fused attention (verified in round 5), unchanged.
// ---------------------------------------------------------------------------
__global__ __launch_bounds__(256, 2) void k_attn(_Float16* __restrict__ qkv) {
  int g = blockIdx.x >> 3, h = blockIdx.x & 7;
  int tid = threadIdx.x, lane = tid & 63, w = tid >> 6;
  int l15 = lane & 15, lg = lane >> 4;
  __shared__ _Float16 Kt[64 * 72];
  __shared__ _Float16 Vt[64 * 72];
  __shared__ _Float16 Pl[4][64 * 72];
  const size_t base = (size_t)g * NSEQ * TRIPLE;

  half8 qf[4][2];
#pragma unroll
  for (int nq = 0; nq < 4; ++nq)
#pragma unroll
    for (int kd = 0; kd < 2; ++kd)
      qf[nq][kd] = *(const half8*)&qkv[base + (size_t)(w * 64 + nq * 16 + l15) * TRIPLE
                                       + h * 64 + kd * 32 + lg * 8];

  f32x4 oacc[4][4] = {};
  float mrun[4], lrun[4];
#pragma unroll
  for (int nq = 0; nq < 4; ++nq) { mrun[nq] = -3.0e38f; lrun[nq] = 0.f; }

  for (int kt = 0; kt < 4; ++kt) {
    __syncthreads();
#pragma unroll
    for (int i = 0; i < 2; ++i) {
      int idx = tid + i * 256;
      int key = idx >> 3, dh0 = (idx & 7) * 8;
      half8 kv = *(const half8*)&qkv[base + (size_t)(kt * 64 + key) * TRIPLE + 512 + h * 64 + dh0];
      *(half8*)&Kt[key * 72 + dh0] = kv;
      half8 vv = *(const half8*)&qkv[base + (size_t)(kt * 64 + key) * TRIPLE + 1024 + h * 64 + dh0];
#pragma unroll
      for (int j = 0; j < 8; ++j) Vt[(dh0 + j) * 72 + key] = vv[j];
    }
    __syncthreads();

    f32x4 st[4][4] = {};
#pragma unroll
    for (int kd = 0; kd < 2; ++kd) {
      int co = kd * 32 + lg * 8;
      half8 kf[4];
#pragma unroll
      for (int mk = 0; mk < 4; ++mk) kf[mk] = *(const half8*)&Kt[(mk * 16 + l15) * 72 + co];
#pragma unroll
      for (int mk = 0; mk < 4; ++mk)
#pragma unroll
        for (int nq = 0; nq < 4; ++nq)
          st[mk][nq] = __builtin_amdgcn_mfma_f32_16x16x32_f16(kf[mk], qf[nq][kd], st[mk][nq], 0, 0, 0);
    }

    float alpha[4];
#pragma unroll
    for (int nq = 0; nq < 4; ++nq) {
      float pm = -3.0e38f;
#pragma unroll
      for (int mk = 0; mk < 4; ++mk)
#pragma unroll
        for (int r = 0; r < 4; ++r) {
          st[mk][nq][r] *= ATT_SCALE;
          pm = fmaxf(pm, st[mk][nq][r]);
        }
      pm = fmaxf(pm, __shfl_xor(pm, 16));
      pm = fmaxf(pm, __shfl_xor(pm, 32));
      float mn = fmaxf(mrun[nq], pm);
      alpha[nq] = __expf(mrun[nq] - mn);
      mrun[nq] = mn;
      float ps = 0.f;
#pragma unroll
      for (int mk = 0; mk < 4; ++mk) {
        half4 p4;
#pragma unroll
        for (int r = 0; r < 4; ++r) {
          float e = __expf(st[mk][nq][r] - mn);
          ps += e;
          p4[r] = (_Float16)e;
        }
        *(half4*)&Pl[w][(nq * 16 + l15) * 72 + mk * 16 + lg * 4] = p4;
      }
      ps += __shfl_xor(ps, 16);
      ps += __shfl_xor(ps, 32);
      lrun[nq] = lrun[nq] * alpha[nq] + ps;
    }

#pragma unroll
    for (int mp = 0; mp < 4; ++mp)
#pragma unroll
      for (int r = 0; r < 4; ++r) {
        float av = __shfl(alpha[mp], lg * 4 + r);
#pragma unroll
        for (int nd = 0; nd < 4; ++nd) oacc[mp][nd][r] *= av;
      }

    __syncthreads();

#pragma unroll
    for (int kp = 0; kp < 2; ++kp) {
      int co = kp * 32 + lg * 8;
      half8 pf[4], vf[4];
#pragma unroll
      for (int mp = 0; mp < 4; ++mp) pf[mp] = *(const half8*)&Pl[w][(mp * 16 + l15) * 72 + co];
#pragma unroll
      for (int nd = 0; nd < 4; ++nd) vf[nd] = *(const half8*)&Vt[(nd * 16 + l15) * 72 + co];
#pragma unroll
      for (int mp = 0; mp < 4; ++mp)
#pragma unroll
        for (int nd = 0; nd < 4; ++nd)
          oacc[mp][nd] = __builtin_amdgcn_mfma_f32_16x16x32_f16(pf[mp], vf[nd], oacc[mp][nd], 0, 0, 0);
    }
  }

#pragma unroll
  for (int mp = 0; mp < 4; ++mp)
#pragma unroll
    for (int r = 0; r < 4; ++r) {
      float li = 1.f / __shfl(lrun[mp], lg * 4 + r);
      int q = w * 64 + mp * 16 + lg * 4 + r;
#pragma unroll
      for (int nd = 0; nd < 4; ++nd)
        qkv[base + (size_t)q * TRIPLE + h * 64 + nd * 16 + l15] =
            (_Float16)(oacc[mp][nd][r] * li);
    }
}

// ---------------------------------------------------------------------------
extern "C" void kernel_launch(void* const* d_in, const int* in_sizes, int n_in,
                              void* d_out, int out_size, void* d_ws, size_t ws_size,
                              hipStream_t stream) {
  const float* x     = (const float*)d_in[0];
  const float* ln_g  = (const float*)d_in[1];
  const float* ln_b  = (const float*)d_in[2];
  const float* w_qkv = (const float*)d_in[3];
  const float* w_out = (const float*)d_in[4];
  const float* b_out = (const float*)d_in[5];

  // workspace (~194 MB): qkv fp16 [65536][1536] (att overwrites Q cols);
  // w_qkv^T fp16; w_out^T fp16. d_out f32 [65536][512]; first 64MB = xn fp16.
  char* ws = (char*)d_ws;
  _Float16* qkv = (_Float16*)ws;
  _Float16* wtq = (_Float16*)(ws + 201326592ull);
  _Float16* wto = (_Float16*)(ws + 201326592ull + 1572864ull);
  _Float16* xn  = (_Float16*)d_out;
  float* out    = (float*)d_out;

  k_wconv<<<4096, 256, 0, stream>>>(w_qkv, w_out, wtq, wto);
  k_ln<<<16384, 256, 0, stream>>>(x, ln_g, ln_b, xn);
  k_gemm8<TRIPLE, DIMD><<<1536, 512, 0, stream>>>(xn, wtq, qkv);
  k_attn<<<2048, 256, 0, stream>>>(qkv);
  k_gemm<DIMD, TRIPLE, true><<<2048, 256, 0, stream>>>(qkv, wto, nullptr, out, b_out);
}

// Round 8
// 288.229 us; speedup vs baseline: 1.1521x; 1.0641x over previous
//
#include <hip/hip_runtime.h>
#include <stdint.h>

// Problem constants
#define DIMD 512
#define HEADS 8
#define DHEAD 64
#define NSEQ 256
#define NGRP 256                 // b*p = 4*64
#define TRIPLE 1536
#define ATT_SCALE 0.125f         // 64^-0.5

typedef float f32x4 __attribute__((ext_vector_type(4)));
typedef _Float16 half8 __attribute__((ext_vector_type(8)));
typedef _Float16 half4 __attribute__((ext_vector_type(4)));

// async global->LDS, 16B per lane; LDS dest = per-wave uniform base + lane*16
#define GLD16(gp, lp) __builtin_amdgcn_global_load_lds( \
    (const __attribute__((address_space(1))) void*)(gp), \
    (__attribute__((address_space(3))) void*)(lp), 16, 0, 0)
#define BAR() __builtin_amdgcn_s_barrier()
#define VMW(n) asm volatile("s_waitcnt vmcnt(" #n ")" ::: "memory")

// ---------------------------------------------------------------------------
// Kernel 0+1 merged: weight convert/transpose (blocks 0..4095) and LayerNorm
// (blocks 4096..20479; one wave per row, vectorized f32 loads, f16 out).
// ---------------------------------------------------------------------------
__global__ __launch_bounds__(256) void k_pre(const float* __restrict__ x,
                                             const float* __restrict__ g,
                                             const float* __restrict__ b,
                                             const float* __restrict__ wq,
                                             const float* __restrict__ wo,
                                             _Float16* __restrict__ xn,
                                             _Float16* __restrict__ wtq,
                                             _Float16* __restrict__ wto) {
  int bid = blockIdx.x;
  if (bid < 4096) {
    int id = bid * 256 + threadIdx.x;          // covers exactly 786432+262144
    if (id < DIMD * TRIPLE) {
      int k = id / TRIPLE, n = id % TRIPLE;
      wtq[n * DIMD + k] = (_Float16)wq[id];
    } else {
      int j = id - DIMD * TRIPLE;
      int k = j / DIMD, n = j % DIMD;
      wto[n * DIMD + k] = (_Float16)wo[j];
    }
    return;
  }
  int row = (bid - 4096) * 4 + (threadIdx.x >> 6);
  int lane = threadIdx.x & 63;
  const float* xr = x + (size_t)row * DIMD + lane * 8;
  float v[8];
  *(f32x4*)(v)     = *(const f32x4*)(xr);
  *(f32x4*)(v + 4) = *(const f32x4*)(xr + 4);
  float s = 0.f, ss = 0.f;
#pragma unroll
  for (int j = 0; j < 8; ++j) { s += v[j]; ss += v[j] * v[j]; }
#pragma unroll
  for (int m = 1; m < 64; m <<= 1) { s += __shfl_xor(s, m); ss += __shfl_xor(ss, m); }
  float mean = s * (1.f / DIMD);
  float var  = ss * (1.f / DIMD) - mean * mean;
  float rstd = rsqrtf(var + 1e-5f);
  const float* gp = g + lane * 8;
  const float* bp = b + lane * 8;
  half8 o;
#pragma unroll
  for (int j = 0; j < 8; ++j) o[j] = (_Float16)((v[j] - mean) * rstd * gp[j] + bp[j]);
  *(half8*)(xn + (size_t)row * DIMD + lane * 8) = o;
}

// ---------------------------------------------------------------------------
// Kernel 2/4: 256x256-tile, BK=64, 8-wave (2Mx4N), phase-split GEMM.
// T1 XCD swizzle, T2 both-sides LDS XOR swizzle, T3+T4 counted vmcnt,
// T5 setprio. Staged halves match per-wave consumption (A: row bit6 == mh;
// B: row bit5 == nh) — verified round 7.
// F32OUT: f32 output + f32 bias (out-projection); else f16 output.
// ---------------------------------------------------------------------------
template <int N, int LDA, bool F32OUT>
__global__ __launch_bounds__(512, 2) void k_gemm8(const _Float16* __restrict__ A,
                                                  const _Float16* __restrict__ BT,
                                                  _Float16* __restrict__ Ch,
                                                  float* __restrict__ Cf,
                                                  const float* __restrict__ bias) {
  constexpr int NT = N / 256;
  constexpr int NWG = 256 * NT;          // 65536/256 m-tiles * NT; NWG % 8 == 0
  constexpr int CPX = NWG / 8;
  int b = blockIdx.x;
  int logical = (b & 7) * CPX + (b >> 3);  // bijective XCD chunking (T1)
  int mt = logical / NT, nt = logical % NT;
  int m0 = mt * 256, n0 = nt * 256;

  int tid = threadIdx.x, lane = tid & 63, w = tid >> 6;   // 8 waves
  int wrow = w >> 2, wcol = w & 3;                        // 2M x 4N
  int l15 = lane & 15, lg = lane >> 4;
  const int sr = lane >> 3;     // staging: row within 8-row stripe
  const int ss = lane & 7;      // staging: 16B slot within 128B row

  // 128 KiB LDS: [buf0: A 16384h | B 16384h][buf1: ...]
  __shared__ _Float16 S[65536];

  f32x4 acc[8][4] = {};          // [mh*4+mf][nh*2+nf]
  half8 af[4][2], bf0[2][2], bf1[2][2];

  // --- staging: A-half-hf = rows with bit6==hf ({0..63,128..191} / rest)
  auto stageA = [&](int d, int kt, int hf) {
#pragma unroll
    for (int cc = 0; cc < 2; ++cc) {
      int rbase = cc * 128 + hf * 64 + w * 8;          // 8-row stripe base
      const _Float16* gp = A + (size_t)(m0 + rbase + sr) * LDA + kt * 64 + (ss ^ sr) * 8;
      _Float16* l = &S[d * 32768 + rbase * 64];
      GLD16(gp, l);
    }
  };
  // --- staging: B-half-hf = rows with bit5==hf
  auto stageB = [&](int d, int kt, int hf) {
#pragma unroll
    for (int cc = 0; cc < 2; ++cc) {
      int i = cc * 64 + w * 8;                         // stripe index in [0,128)
      int rbase = (i >> 5) * 64 + hf * 32 + (i & 31);  // 8-row stripe base
      const _Float16* gp = BT + (size_t)(n0 + rbase + sr) * 512 + kt * 64 + (ss ^ sr) * 8;
      _Float16* l = &S[d * 32768 + 16384 + rbase * 64];
      GLD16(gp, l);
    }
  };
  // --- LDS -> register fragments (swizzled read, matches source permutation)
  auto loadA = [&](int c, int mh) {
#pragma unroll
    for (int mf = 0; mf < 4; ++mf) {
      int row = wrow * 128 + mh * 64 + mf * 16 + l15;  // bit6 == mh
#pragma unroll
      for (int kk = 0; kk < 2; ++kk) {
        int byte = row * 128 + ((kk * 64 + lg * 16) ^ ((row & 7) << 4));
        af[mf][kk] = *(const half8*)((const char*)&S[c * 32768] + byte);
      }
    }
  };
  auto loadB = [&](int c, int nh, half8 (&bf)[2][2]) {
#pragma unroll
    for (int nf = 0; nf < 2; ++nf) {
      int row = wcol * 64 + nh * 32 + nf * 16 + l15;   // bit5 == nh
#pragma unroll
      for (int kk = 0; kk < 2; ++kk) {
        int byte = row * 128 + ((kk * 64 + lg * 16) ^ ((row & 7) << 4));
        bf[nf][kk] = *(const half8*)((const char*)&S[c * 32768 + 16384] + byte);
      }
    }
  };
  auto quad = [&](int mh, int nh, half8 (&bf)[2][2]) {
    __builtin_amdgcn_s_setprio(1);
#pragma unroll
    for (int mf = 0; mf < 4; ++mf)
#pragma unroll
      for (int nf = 0; nf < 2; ++nf)
#pragma unroll
        for (int kk = 0; kk < 2; ++kk)
          acc[mh * 4 + mf][nh * 2 + nf] = __builtin_amdgcn_mfma_f32_16x16x32_f16(
              af[mf][kk], bf[nf][kk], acc[mh * 4 + mf][nh * 2 + nf], 0, 0, 0);
    __builtin_amdgcn_s_setprio(0);
  };

  // --- prologue: stage tile 0; order A0,B0,B1,A1 so VMW(4) => A-h0,B-h0 landed
  stageA(0, 0, 0); stageB(0, 0, 0); stageB(0, 0, 1); stageA(0, 0, 1);
  VMW(4); BAR();

  // --- main loop: consume tile t (buffer c), stage t+1 (buffer d).
  // FIFO invariant at entry: [B-h1(t):2, A-h1(t):2]
  for (int t = 0; t < 7; ++t) {
    int c = t & 1, d = c ^ 1;
    loadA(c, 0); loadB(c, 0, bf0);
    stageA(d, t + 1, 0);
    BAR(); quad(0, 0, bf0); VMW(4); BAR();   // -> B-h1(t) landed
    loadB(c, 1, bf1);
    stageB(d, t + 1, 0);
    BAR(); quad(0, 1, bf1); VMW(4); BAR();   // -> A-h1(t) landed
    loadA(c, 1);
    stageB(d, t + 1, 1);
    BAR(); quad(1, 0, bf0); BAR();           // ph4 reads no LDS: no wait
    stageA(d, t + 1, 1);
    BAR(); quad(1, 1, bf1); VMW(4); BAR();   // -> A-h0,B-h0(t+1) landed
  }
  // --- last tile t=7 (c=1): no staging; drain just-in-time
  {
    loadA(1, 0); loadB(1, 0, bf0);
    BAR(); quad(0, 0, bf0); VMW(2); BAR();   // -> B-h1(7) landed
    loadB(1, 1, bf1);
    BAR(); quad(0, 1, bf1); VMW(0); BAR();   // -> A-h1(7) landed
    loadA(1, 1);
    BAR(); quad(1, 0, bf0); BAR();
    BAR(); quad(1, 1, bf1); BAR();
  }

  // --- epilogue
  float bb[4];
  if constexpr (F32OUT) {
#pragma unroll
    for (int nq = 0; nq < 4; ++nq)
      bb[nq] = bias[n0 + wcol * 64 + (nq >> 1) * 32 + (nq & 1) * 16 + l15];
  }
#pragma unroll
  for (int mq = 0; mq < 8; ++mq)
#pragma unroll
    for (int nq = 0; nq < 4; ++nq)
#pragma unroll
      for (int r = 0; r < 4; ++r) {
        int row = m0 + wrow * 128 + (mq >> 2) * 64 + (mq & 3) * 16 + lg * 4 + r;
        int col = n0 + wcol * 64 + (nq >> 1) * 32 + (nq & 1) * 16 + l15;
        if constexpr (F32OUT)
          Cf[(size_t)row * N + col] = acc[mq][nq][r] + bb[nq];
        else
          Ch[(size_t)row * N + col] = (_Float16)acc[mq][nq][r];
      }
}

// ---------------------------------------------------------------------------
// Kernel 3: fused attention, one block per (group, head). 4 waves x 64 q-rows.
// K staged via global_load_lds into unpadded swizzled Kt (gemm8's exact
// source/read XOR pair); V reg-transposed into padded Vt. Swapped QK^T,
// online softmax, P via LDS, output into dead Q columns of qkv.
// ---------------------------------------------------------------------------
__global__ __launch_bounds__(256, 2) void k_attn(_Float16* __restrict__ qkv) {
  int g = blockIdx.x >> 3, h = blockIdx.x & 7;
  int tid = threadIdx.x, lane = tid & 63, w = tid >> 6;
  int l15 = lane & 15, lg = lane >> 4;
  __shared__ _Float16 Kt[64 * 64];          // [key][dh], unpadded, XOR-swizzled
  __shared__ _Float16 Vt[64 * 72];          // [dh][key] (transposed), padded
  __shared__ _Float16 Pl[4][64 * 72];       // per-wave P[q][key], padded
  const size_t base = (size_t)g * NSEQ * TRIPLE;

  // Q fragments (B-operand layout): q col = l15 + nq*16, dh contiguous
  half8 qf[4][2];
#pragma unroll
  for (int nq = 0; nq < 4; ++nq)
#pragma unroll
    for (int kd = 0; kd < 2; ++kd)
      qf[nq][kd] = *(const half8*)&qkv[base + (size_t)(w * 64 + nq * 16 + l15) * TRIPLE
                                       + h * 64 + kd * 32 + lg * 8];

  f32x4 oacc[4][4] = {};
  float mrun[4], lrun[4];
#pragma unroll
  for (int nq = 0; nq < 4; ++nq) { mrun[nq] = -3.0e38f; lrun[nq] = 0.f; }

  const int srow = lane >> 3;      // staging row within 8-row stripe
  const int sslot = lane & 7;      // staging 16B slot

  for (int kt = 0; kt < 4; ++kt) {
    __syncthreads();     // protect LDS overwrite vs previous iteration's PV
    // K tile: global_load_lds, pre-swizzled source (slot ^ row&7), linear dest
#pragma unroll
    for (int rnd = 0; rnd < 2; ++rnd) {
      int rbase = rnd * 32 + w * 8;                        // wave's 8-row stripe
      const _Float16* gp = &qkv[base + (size_t)(kt * 64 + rbase + srow) * TRIPLE
                                + 512 + h * 64 + (sslot ^ srow) * 8];
      GLD16(gp, &Kt[rbase * 64]);
    }
    // V^T tile: reg roundtrip + transpose into padded rows
#pragma unroll
    for (int i = 0; i < 2; ++i) {
      int idx = tid + i * 256;
      int key = idx >> 3, dh0 = (idx & 7) * 8;
      half8 vv = *(const half8*)&qkv[base + (size_t)(kt * 64 + key) * TRIPLE + 1024 + h * 64 + dh0];
#pragma unroll
      for (int j = 0; j < 8; ++j) Vt[(dh0 + j) * 72 + key] = vv[j];
    }
    VMW(0);
    __syncthreads();

    // S^T = K * Q^T
    f32x4 st[4][4] = {};
#pragma unroll
    for (int kd = 0; kd < 2; ++kd) {
      half8 kf[4];
#pragma unroll
      for (int mk = 0; mk < 4; ++mk) {
        int r = mk * 16 + l15;
        int byte = r * 128 + ((kd * 64 + lg * 16) ^ ((r & 7) << 4));
        kf[mk] = *(const half8*)((const char*)Kt + byte);
      }
#pragma unroll
      for (int mk = 0; mk < 4; ++mk)
#pragma unroll
        for (int nq = 0; nq < 4; ++nq)
          st[mk][nq] = __builtin_amdgcn_mfma_f32_16x16x32_f16(kf[mk], qf[nq][kd], st[mk][nq], 0, 0, 0);
    }

    // online softmax per q column (nq, l15); key axis = (mk, lg, r)
    float alpha[4];
#pragma unroll
    for (int nq = 0; nq < 4; ++nq) {
      float pm = -3.0e38f;
#pragma unroll
      for (int mk = 0; mk < 4; ++mk)
#pragma unroll
        for (int r = 0; r < 4; ++r) {
          st[mk][nq][r] *= ATT_SCALE;
          pm = fmaxf(pm, st[mk][nq][r]);
        }
      pm = fmaxf(pm, __shfl_xor(pm, 16));
      pm = fmaxf(pm, __shfl_xor(pm, 32));
      float mn = fmaxf(mrun[nq], pm);
      alpha[nq] = __expf(mrun[nq] - mn);
      mrun[nq] = mn;
      float ps = 0.f;
#pragma unroll
      for (int mk = 0; mk < 4; ++mk) {
        half4 p4;
#pragma unroll
        for (int r = 0; r < 4; ++r) {
          float e = __expf(st[mk][nq][r] - mn);
          ps += e;
          p4[r] = (_Float16)e;
        }
        *(half4*)&Pl[w][(nq * 16 + l15) * 72 + mk * 16 + lg * 4] = p4;
      }
      ps += __shfl_xor(ps, 16);
      ps += __shfl_xor(ps, 32);
      lrun[nq] = lrun[nq] * alpha[nq] + ps;
    }

    // rescale O: O row q = mp*16 + lg*4 + r, alpha lives at lanes l15 == q&15
#pragma unroll
    for (int mp = 0; mp < 4; ++mp)
#pragma unroll
      for (int r = 0; r < 4; ++r) {
        float av = __shfl(alpha[mp], lg * 4 + r);
#pragma unroll
        for (int nd = 0; nd < 4; ++nd) oacc[mp][nd][r] *= av;
      }

    __syncthreads();   // P visible (also keeps waves in lockstep)

    // O += P * V
#pragma unroll
    for (int kp = 0; kp < 2; ++kp) {
      int co = kp * 32 + lg * 8;
      half8 pf[4], vf[4];
#pragma unroll
      for (int mp = 0; mp < 4; ++mp) pf[mp] = *(const half8*)&Pl[w][(mp * 16 + l15) * 72 + co];
#pragma unroll
      for (int nd = 0; nd < 4; ++nd) vf[nd] = *(const half8*)&Vt[(nd * 16 + l15) * 72 + co];
#pragma unroll
      for (int mp = 0; mp < 4; ++mp)
#pragma unroll
        for (int nd = 0; nd < 4; ++nd)
          oacc[mp][nd] = __builtin_amdgcn_mfma_f32_16x16x32_f16(pf[mp], vf[nd], oacc[mp][nd], 0, 0, 0);
    }
  }

  // epilogue: normalize and write att into the Q columns (stride TRIPLE)
#pragma unroll
  for (int mp = 0; mp < 4; ++mp)
#pragma unroll
    for (int r = 0; r < 4; ++r) {
      float li = 1.f / __shfl(lrun[mp], lg * 4 + r);
      int q = w * 64 + mp * 16 + lg * 4 + r;
#pragma unroll
      for (int nd = 0; nd < 4; ++nd)
        qkv[base + (size_t)q * TRIPLE + h * 64 + nd * 16 + l15] =
            (_Float16)(oacc[mp][nd][r] * li);
    }
}

// ---------------------------------------------------------------------------
extern "C" void kernel_launch(void* const* d_in, const int* in_sizes, int n_in,
                              void* d_out, int out_size, void* d_ws, size_t ws_size,
                              hipStream_t stream) {
  const float* x     = (const float*)d_in[0];
  const float* ln_g  = (const float*)d_in[1];
  const float* ln_b  = (const float*)d_in[2];
  const float* w_qkv = (const float*)d_in[3];
  const float* w_out = (const float*)d_in[4];
  const float* b_out = (const float*)d_in[5];

  // workspace (~194 MB): qkv fp16 [65536][1536] (att overwrites Q cols);
  // w_qkv^T fp16; w_out^T fp16. d_out f32 [65536][512]; first 64MB = xn fp16.
  char* ws = (char*)d_ws;
  _Float16* qkv = (_Float16*)ws;
  _Float16* wtq = (_Float16*)(ws + 201326592ull);
  _Float16* wto = (_Float16*)(ws + 201326592ull + 1572864ull);
  _Float16* xn  = (_Float16*)d_out;
  float* out    = (float*)d_out;

  k_pre<<<20480, 256, 0, stream>>>(x, ln_g, ln_b, w_qkv, w_out, xn, wtq, wto);
  k_gemm8<TRIPLE, DIMD, false><<<1536, 512, 0, stream>>>(xn, wtq, qkv, nullptr, nullptr);
  k_attn<<<2048, 256, 0, stream>>>(qkv);
  k_gemm8<DIMD, TRIPLE, true><<<512, 512, 0, stream>>>(qkv, wto, nullptr, out, b_out);
}

// Round 9
// 278.773 us; speedup vs baseline: 1.1912x; 1.0339x over previous
//
#include <hip/hip_runtime.h>
#include <stdint.h>

// Problem constants
#define DIMD 512
#define HEADS 8
#define DHEAD 64
#define NSEQ 256
#define NGRP 256                 // b*p = 4*64
#define TRIPLE 1536
#define ATT_SCALE 0.125f         // 64^-0.5

typedef float f32x4 __attribute__((ext_vector_type(4)));
typedef _Float16 half8 __attribute__((ext_vector_type(8)));
typedef _Float16 half4 __attribute__((ext_vector_type(4)));

// async global->LDS, 16B per lane; LDS dest = per-wave uniform base + lane*16
#define GLD16(gp, lp) __builtin_amdgcn_global_load_lds( \
    (const __attribute__((address_space(1))) void*)(gp), \
    (__attribute__((address_space(3))) void*)(lp), 16, 0, 0)
#define BAR() __builtin_amdgcn_s_barrier()
#define VMW(n) asm volatile("s_waitcnt vmcnt(" #n ")" ::: "memory")

// ---------------------------------------------------------------------------
// Kernel 0+1 merged: blocks 0..255 = tiled 64x64 LDS transpose of weights
// (coalesced reads AND writes); blocks 256..16639 = LayerNorm (wave per row).
// ---------------------------------------------------------------------------
__global__ __launch_bounds__(256) void k_pre(const float* __restrict__ x,
                                             const float* __restrict__ g,
                                             const float* __restrict__ b,
                                             const float* __restrict__ wq,
                                             const float* __restrict__ wo,
                                             _Float16* __restrict__ xn,
                                             _Float16* __restrict__ wtq,
                                             _Float16* __restrict__ wto) {
  int bid = blockIdx.x;
  if (bid < 256) {
    __shared__ float T[64][65];
    const float* src; _Float16* dst; int spitch, ti, tj;
    if (bid < 192) { src = wq; dst = wtq; spitch = TRIPLE; ti = bid / 24; tj = bid % 24; }
    else { int t = bid - 192; src = wo; dst = wto; spitch = DIMD; ti = t >> 3; tj = t & 7; }
    // read 64x64 f32 tile (row = k dim, col = n dim), coalesced
#pragma unroll
    for (int it = 0; it < 4; ++it) {
      int idx = it * 256 + threadIdx.x;
      int rr = idx >> 4, c4 = (idx & 15) * 4;
      *(f32x4*)&T[rr][c4] = *(const f32x4*)&src[(size_t)(ti * 64 + rr) * spitch + tj * 64 + c4];
    }
    __syncthreads();
    // write transposed, coalesced: dst[(n)(DIMD) + k]
#pragma unroll
    for (int it = 0; it < 2; ++it) {
      int idx = it * 256 + threadIdx.x;
      int rr2 = idx >> 3, c8 = (idx & 7) * 8;
      half8 o;
#pragma unroll
      for (int j = 0; j < 8; ++j) o[j] = (_Float16)T[c8 + j][rr2];
      *(half8*)&dst[(size_t)(tj * 64 + rr2) * DIMD + ti * 64 + c8] = o;
    }
    return;
  }
  int row = (bid - 256) * 4 + (threadIdx.x >> 6);
  int lane = threadIdx.x & 63;
  const float* xr = x + (size_t)row * DIMD + lane * 8;
  float v[8];
  *(f32x4*)(v)     = *(const f32x4*)(xr);
  *(f32x4*)(v + 4) = *(const f32x4*)(xr + 4);
  float s = 0.f, ss = 0.f;
#pragma unroll
  for (int j = 0; j < 8; ++j) { s += v[j]; ss += v[j] * v[j]; }
#pragma unroll
  for (int m = 1; m < 64; m <<= 1) { s += __shfl_xor(s, m); ss += __shfl_xor(ss, m); }
  float mean = s * (1.f / DIMD);
  float var  = ss * (1.f / DIMD) - mean * mean;
  float rstd = rsqrtf(var + 1e-5f);
  const float* gp = g + lane * 8;
  const float* bp = b + lane * 8;
  half8 o;
#pragma unroll
  for (int j = 0; j < 8; ++j) o[j] = (_Float16)((v[j] - mean) * rstd * gp[j] + bp[j]);
  *(half8*)(xn + (size_t)row * DIMD + lane * 8) = o;
}

// ---------------------------------------------------------------------------
// Kernel 2/4: 256x256-tile, BK=64, 8-wave phase-split GEMM, pipelined by one
// phase: quad(1,1) of tile t runs in R1 of t+1, and every quad overlaps the
// NEXT quad's ds_reads. 4 barriers/tile. Stage order A0,B0,B1,A1 and VMW
// counts identical (same FIFO states) to the verified round-7 schedule:
//   entry inv [B1(c):2, A1(c):2]; R1 VMW(4)->B1(c); R2 VMW(4)->A1(c);
//   R4 VMW(4)->A0,B0(d) = entry inv. Tail drains VMW(2)/VMW(0).
// T1 XCD swizzle, T2 both-sides XOR swizzle, T5 setprio.
// ---------------------------------------------------------------------------
template <int N, int LDA, bool F32OUT>
__global__ __launch_bounds__(512, 2) void k_gemm8(const _Float16* __restrict__ A,
                                                  const _Float16* __restrict__ BT,
                                                  _Float16* __restrict__ Ch,
                                                  float* __restrict__ Cf,
                                                  const float* __restrict__ bias) {
  constexpr int NT = N / 256;
  constexpr int NWG = 256 * NT;          // NWG % 8 == 0
  constexpr int CPX = NWG / 8;
  int bb_ = blockIdx.x;
  int logical = (bb_ & 7) * CPX + (bb_ >> 3);  // bijective XCD chunking (T1)
  int mt = logical / NT, nt = logical % NT;
  int m0 = mt * 256, n0 = nt * 256;

  int tid = threadIdx.x, lane = tid & 63, w = tid >> 6;   // 8 waves
  int wrow = w >> 2, wcol = w & 3;                        // 2M x 4N
  int l15 = lane & 15, lg = lane >> 4;
  const int sr = lane >> 3;     // staging: row within 8-row stripe
  const int ss = lane & 7;      // staging: 16B slot within 128B row

  __shared__ _Float16 S[65536];  // [buf0: A 16384h | B 16384h][buf1: ...]

  f32x4 acc[8][4] = {};          // [mh*4+mf][nh*2+nf]
  half8 af0[4][2], af1[4][2], bf0[2][2], bf1[2][2];

  // --- staging: A-half-hf = rows with bit6==hf; B-half-hf = rows with bit5==hf
  auto stageA = [&](int d, int kt, int hf) {
#pragma unroll
    for (int cc = 0; cc < 2; ++cc) {
      int rbase = cc * 128 + hf * 64 + w * 8;
      const _Float16* gp = A + (size_t)(m0 + rbase + sr) * LDA + kt * 64 + (ss ^ sr) * 8;
      GLD16(gp, &S[d * 32768 + rbase * 64]);
    }
  };
  auto stageB = [&](int d, int kt, int hf) {
#pragma unroll
    for (int cc = 0; cc < 2; ++cc) {
      int i = cc * 64 + w * 8;
      int rbase = (i >> 5) * 64 + hf * 32 + (i & 31);
      const _Float16* gp = BT + (size_t)(n0 + rbase + sr) * 512 + kt * 64 + (ss ^ sr) * 8;
      GLD16(gp, &S[d * 32768 + 16384 + rbase * 64]);
    }
  };
  auto loadA = [&](int c, int mh, half8 (&af)[4][2]) {
#pragma unroll
    for (int mf = 0; mf < 4; ++mf) {
      int row = wrow * 128 + mh * 64 + mf * 16 + l15;  // bit6 == mh
#pragma unroll
      for (int kk = 0; kk < 2; ++kk) {
        int byte = row * 128 + ((kk * 64 + lg * 16) ^ ((row & 7) << 4));
        af[mf][kk] = *(const half8*)((const char*)&S[c * 32768] + byte);
      }
    }
  };
  auto loadB = [&](int c, int nh, half8 (&bf)[2][2]) {
#pragma unroll
    for (int nf = 0; nf < 2; ++nf) {
      int row = wcol * 64 + nh * 32 + nf * 16 + l15;   // bit5 == nh
#pragma unroll
      for (int kk = 0; kk < 2; ++kk) {
        int byte = row * 128 + ((kk * 64 + lg * 16) ^ ((row & 7) << 4));
        bf[nf][kk] = *(const half8*)((const char*)&S[c * 32768 + 16384] + byte);
      }
    }
  };
  auto quad = [&](int mh, int nh, half8 (&af)[4][2], half8 (&bf)[2][2]) {
    __builtin_amdgcn_s_setprio(1);
#pragma unroll
    for (int mf = 0; mf < 4; ++mf)
#pragma unroll
      for (int nf = 0; nf < 2; ++nf)
#pragma unroll
        for (int kk = 0; kk < 2; ++kk)
          acc[mh * 4 + mf][nh * 2 + nf] = __builtin_amdgcn_mfma_f32_16x16x32_f16(
              af[mf][kk], bf[nf][kk], acc[mh * 4 + mf][nh * 2 + nf], 0, 0, 0);
    __builtin_amdgcn_s_setprio(0);
  };

  // --- prologue: stage tile 0; VMW(4) => A0,B0 landed, leaves [B1:2, A1:2]
  stageA(0, 0, 0); stageB(0, 0, 0); stageB(0, 0, 1); stageA(0, 0, 1);
  VMW(4); BAR();

#pragma unroll
  for (int t = 0; t < 8; ++t) {
    const int c = t & 1, d = c ^ 1;
    // R1: prefetch A0,B0(c); run previous tile's quad(1,1)
    loadA(c, 0, af0); loadB(c, 0, bf0);
    if (t > 0) quad(1, 1, af1, bf1);
    if (t < 7) { stageA(d, t + 1, 0); VMW(4); } else { VMW(2); }   // -> B1(c)
    BAR();
    // R2: prefetch B1(c); quad(0,0)
    loadB(c, 1, bf1);
    quad(0, 0, af0, bf0);
    if (t < 7) { stageB(d, t + 1, 0); VMW(4); } else { VMW(0); }   // -> A1(c)
    BAR();
    // R3: prefetch A1(c); quad(0,1)
    loadA(c, 1, af1);
    quad(0, 1, af0, bf1);
    if (t < 7) stageB(d, t + 1, 1);
    BAR();
    // R4: quad(1,0)
    quad(1, 0, af1, bf0);
    if (t < 7) { stageA(d, t + 1, 1); VMW(4); }                    // -> A0,B0(d)
    BAR();
  }
  quad(1, 1, af1, bf1);   // tile 7's last quad

  // --- epilogue
  float bbv[4];
  if constexpr (F32OUT) {
#pragma unroll
    for (int nq = 0; nq < 4; ++nq)
      bbv[nq] = bias[n0 + wcol * 64 + (nq >> 1) * 32 + (nq & 1) * 16 + l15];
  }
#pragma unroll
  for (int mq = 0; mq < 8; ++mq)
#pragma unroll
    for (int nq = 0; nq < 4; ++nq)
#pragma unroll
      for (int r = 0; r < 4; ++r) {
        int row = m0 + wrow * 128 + (mq >> 2) * 64 + (mq & 3) * 16 + lg * 4 + r;
        int col = n0 + wcol * 64 + (nq >> 1) * 32 + (nq & 1) * 16 + l15;
        if constexpr (F32OUT)
          Cf[(size_t)row * N + col] = acc[mq][nq][r] + bbv[nq];
        else
          Ch[(size_t)row * N + col] = (_Float16)acc[mq][nq][r];
      }
}

// ---------------------------------------------------------------------------
// Kernel 3: fused attention (verified round 8), unchanged.
// ---------------------------------------------------------------------------
__global__ __launch_bounds__(256, 2) void k_attn(_Float16* __restrict__ qkv) {
  int g = blockIdx.x >> 3, h = blockIdx.x & 7;
  int tid = threadIdx.x, lane = tid & 63, w = tid >> 6;
  int l15 = lane & 15, lg = lane >> 4;
  __shared__ _Float16 Kt[64 * 64];          // [key][dh], unpadded, XOR-swizzled
  __shared__ _Float16 Vt[64 * 72];          // [dh][key] (transposed), padded
  __shared__ _Float16 Pl[4][64 * 72];       // per-wave P[q][key], padded
  const size_t base = (size_t)g * NSEQ * TRIPLE;

  half8 qf[4][2];
#pragma unroll
  for (int nq = 0; nq < 4; ++nq)
#pragma unroll
    for (int kd = 0; kd < 2; ++kd)
      qf[nq][kd] = *(const half8*)&qkv[base + (size_t)(w * 64 + nq * 16 + l15) * TRIPLE
                                       + h * 64 + kd * 32 + lg * 8];

  f32x4 oacc[4][4] = {};
  float mrun[4], lrun[4];
#pragma unroll
  for (int nq = 0; nq < 4; ++nq) { mrun[nq] = -3.0e38f; lrun[nq] = 0.f; }

  const int srow = lane >> 3;
  const int sslot = lane & 7;

  for (int kt = 0; kt < 4; ++kt) {
    __syncthreads();
#pragma unroll
    for (int rnd = 0; rnd < 2; ++rnd) {
      int rbase = rnd * 32 + w * 8;
      const _Float16* gp = &qkv[base + (size_t)(kt * 64 + rbase + srow) * TRIPLE
                                + 512 + h * 64 + (sslot ^ srow) * 8];
      GLD16(gp, &Kt[rbase * 64]);
    }
#pragma unroll
    for (int i = 0; i < 2; ++i) {
      int idx = tid + i * 256;
      int key = idx >> 3, dh0 = (idx & 7) * 8;
      half8 vv = *(const half8*)&qkv[base + (size_t)(kt * 64 + key) * TRIPLE + 1024 + h * 64 + dh0];
#pragma unroll
      for (int j = 0; j < 8; ++j) Vt[(dh0 + j) * 72 + key] = vv[j];
    }
    VMW(0);
    __syncthreads();

    f32x4 st[4][4] = {};
#pragma unroll
    for (int kd = 0; kd < 2; ++kd) {
      half8 kf[4];
#pragma unroll
      for (int mk = 0; mk < 4; ++mk) {
        int r = mk * 16 + l15;
        int byte = r * 128 + ((kd * 64 + lg * 16) ^ ((r & 7) << 4));
        kf[mk] = *(const half8*)((const char*)Kt + byte);
      }
#pragma unroll
      for (int mk = 0; mk < 4; ++mk)
#pragma unroll
        for (int nq = 0; nq < 4; ++nq)
          st[mk][nq] = __builtin_amdgcn_mfma_f32_16x16x32_f16(kf[mk], qf[nq][kd], st[mk][nq], 0, 0, 0);
    }

    float alpha[4];
#pragma unroll
    for (int nq = 0; nq < 4; ++nq) {
      float pm = -3.0e38f;
#pragma unroll
      for (int mk = 0; mk < 4; ++mk)
#pragma unroll
        for (int r = 0; r < 4; ++r) {
          st[mk][nq][r] *= ATT_SCALE;
          pm = fmaxf(pm, st[mk][nq][r]);
        }
      pm = fmaxf(pm, __shfl_xor(pm, 16));
      pm = fmaxf(pm, __shfl_xor(pm, 32));
      float mn = fmaxf(mrun[nq], pm);
      alpha[nq] = __expf(mrun[nq] - mn);
      mrun[nq] = mn;
      float ps = 0.f;
#pragma unroll
      for (int mk = 0; mk < 4; ++mk) {
        half4 p4;
#pragma unroll
        for (int r = 0; r < 4; ++r) {
          float e = __expf(st[mk][nq][r] - mn);
          ps += e;
          p4[r] = (_Float16)e;
        }
        *(half4*)&Pl[w][(nq * 16 + l15) * 72 + mk * 16 + lg * 4] = p4;
      }
      ps += __shfl_xor(ps, 16);
      ps += __shfl_xor(ps, 32);
      lrun[nq] = lrun[nq] * alpha[nq] + ps;
    }

#pragma unroll
    for (int mp = 0; mp < 4; ++mp)
#pragma unroll
      for (int r = 0; r < 4; ++r) {
        float av = __shfl(alpha[mp], lg * 4 + r);
#pragma unroll
        for (int nd = 0; nd < 4; ++nd) oacc[mp][nd][r] *= av;
      }

    __syncthreads();

#pragma unroll
    for (int kp = 0; kp < 2; ++kp) {
      int co = kp * 32 + lg * 8;
      half8 pf[4], vf[4];
#pragma unroll
      for (int mp = 0; mp < 4; ++mp) pf[mp] = *(const half8*)&Pl[w][(mp * 16 + l15) * 72 + co];
#pragma unroll
      for (int nd = 0; nd < 4; ++nd) vf[nd] = *(const half8*)&Vt[(nd * 16 + l15) * 72 + co];
#pragma unroll
      for (int mp = 0; mp < 4; ++mp)
#pragma unroll
        for (int nd = 0; nd < 4; ++nd)
          oacc[mp][nd] = __builtin_amdgcn_mfma_f32_16x16x32_f16(pf[mp], vf[nd], oacc[mp][nd], 0, 0, 0);
    }
  }

#pragma unroll
  for (int mp = 0; mp < 4; ++mp)
#pragma unroll
    for (int r = 0; r < 4; ++r) {
      float li = 1.f / __shfl(lrun[mp], lg * 4 + r);
      int q = w * 64 + mp * 16 + lg * 4 + r;
#pragma unroll
      for (int nd = 0; nd < 4; ++nd)
        qkv[base + (size_t)q * TRIPLE + h * 64 + nd * 16 + l15] =
            (_Float16)(oacc[mp][nd][r] * li);
    }
}

// ---------------------------------------------------------------------------
extern "C" void kernel_launch(void* const* d_in, const int* in_sizes, int n_in,
                              void* d_out, int out_size, void* d_ws, size_t ws_size,
                              hipStream_t stream) {
  const float* x     = (const float*)d_in[0];
  const float* ln_g  = (const float*)d_in[1];
  const float* ln_b  = (const float*)d_in[2];
  const float* w_qkv = (const float*)d_in[3];
  const float* w_out = (const float*)d_in[4];
  const float* b_out = (const float*)d_in[5];

  // workspace (~194 MB): qkv fp16 [65536][1536] (att overwrites Q cols);
  // w_qkv^T fp16; w_out^T fp16. d_out f32 [65536][512]; first 64MB = xn fp16.
  char* ws = (char*)d_ws;
  _Float16* qkv = (_Float16*)ws;
  _Float16* wtq = (_Float16*)(ws + 201326592ull);
  _Float16* wto = (_Float16*)(ws + 201326592ull + 1572864ull);
  _Float16* xn  = (_Float16*)d_out;
  float* out    = (float*)d_out;

  k_pre<<<16640, 256, 0, stream>>>(x, ln_g, ln_b, w_qkv, w_out, xn, wtq, wto);
  k_gemm8<TRIPLE, DIMD, false><<<1536, 512, 0, stream>>>(xn, wtq, qkv, nullptr, nullptr);
  k_attn<<<2048, 256, 0, stream>>>(qkv);
  k_gemm8<DIMD, TRIPLE, true><<<512, 512, 0, stream>>>(qkv, wto, nullptr, out, b_out);
}